// Round 12
// baseline (93.042 us; speedup 1.0000x reference)
//
#include <hip/hip_runtime.h>
#include <stdint.h>

typedef __attribute__((ext_vector_type(4))) float f32x4;
typedef __attribute__((ext_vector_type(4))) unsigned int u32x4;
typedef __attribute__((ext_vector_type(2))) long long i64x2;
typedef long long i64_t;

#define NB 16
#define NC 128
#define NH 128
#define NW 128
#define WP 130

__device__ __forceinline__ int swz7(int wp) { return (wp ^ (wp >> 3)) & 7; }

// ---------------- prep: wfrag (B sign bytes) + sf = mean|w| + theta ----------------
// wfrag flat byte f = p*8192 + kb*2048 + nip*1024 + l*16 + nl*8 + j   (ni = nip*2+nl)
// o = ni*16 + (l&15)
// plain-unit K mapping (validated r7): instr kb, lane lg holds 8-block
// {2lg,2lg+1,2lg+8,2lg+9}[kb]  ->  c = lg*16 + (kb&1)*8 + (kb>>1)*64 + j
__global__ __launch_bounds__(256) void k_prep(const float* __restrict__ cw,
                                              const float* __restrict__ b1,
                                              const float* __restrict__ pa,
                                              const float* __restrict__ b2,
                                              float* __restrict__ sf,
                                              float* __restrict__ theta,
                                              unsigned char* __restrict__ wf) {
    int b = blockIdx.x, t = threadIdx.x;    // 288 blocks
    int f = b * 256 + t;                    // < 73728
    int j   = f & 7;
    int kb  = (f >> 11) & 3;
    int p   = f >> 13;
    int l   = (f >> 4) & 63;
    int lg = (l >> 4) & 3;
    int nl  = (f >> 3) & 1;
    int nip = (f >> 10) & 1;
    int o = (nip * 2 + nl) * 16 + (l & 15);
    int c = lg * 16 + (kb & 1) * 8 + (kb >> 1) * 64 + j;   // plain-unit K mapping
    float wv = cw[o * 1152 + c * 9 + p];
    wf[f] = wv > 0.f ? (unsigned char)0x38
                     : (wv < 0.f ? (unsigned char)0xB8 : (unsigned char)0x00);
    if (b < 64) {                           // sf[b] = mean|w| over 1152
        __shared__ float red[4];
        const float* pp = cw + b * 1152;
        float s = 0.f;
        for (int i = t; i < 1152; i += 256) s += fabsf(pp[i]);
#pragma unroll
        for (int off = 32; off > 0; off >>= 1) s += __shfl_down(s, off);
        if ((t & 63) == 0) red[t >> 6] = s;
        __syncthreads();
        if (t == 0) sf[b] = (red[0] + red[1] + red[2] + red[3]) * (1.0f / 1152.0f);
    }
    if (b == 64 && t < NC) {                // theta: sign(prelu(v+b1)+b2) == sign(v - theta)
        float B1 = b1[t], A = pa[t], B2 = b2[t];   // prelu slope a>0 -> monotone
        theta[t] = (-B2 >= 0.f) ? (-B1 - B2) : (-B1 - B2 / A);
    }
}

__device__ __forceinline__ unsigned int pk8(float v, float th) {
    return v > th ? 0x38u : (v < th ? 0xB8u : 0u);
}

// ---------------- fused: stage signs of 4 padded x-rows into LDS (coalesced f32x4,
// register transpose, two-sided swz7 swizzle applied AT THE ACTUAL COLUMN on both
// sides — r11 bug was reusing base-column swizzle for mi=1..3), shortcut -> out
// during staging, implicit-GEMM fp8 MFMA, epilogue RMW out += conv*sf. ----------------
__global__ __launch_bounds__(256, 2) void k_fused(
    const float* __restrict__ x, const float* __restrict__ theta,
    const float* __restrict__ pw, const unsigned char* __restrict__ wf,
    const float* __restrict__ sf, float* __restrict__ out) {
    __shared__ __align__(16) unsigned char AT[4 * WP * NC];   // 66560 B
    int bxr = blockIdx.x;
    int bx = (bxr & 7) * 128 + (bxr >> 3);  // XCD swizzle (1024 % 8 == 0, bijective)
    int nb = bx >> 6;
    int h2b = bx & 63;
    int t = threadIdx.x;
    int wid = t >> 6;
    int l = t & 63;
    int lr = l & 15, lg = l >> 4;

    // ---- pad columns wp=0, 129 (zeros, swizzled slots) ----
    if (t < 64) {
        int rho = t >> 4, side = (t >> 3) & 1, u = t & 7;
        int wp = side ? (WP - 1) : 0;
        u32x4 z = {0u, 0u, 0u, 0u};
        *(u32x4*)(AT + (size_t)(rho * WP + wp) * NC + ((u ^ swz7(wp)) << 4)) = z;
    }

    // ---- staging: thread (w4 = t&31, cg = t>>5), 16 f32x4 loads per row ----
    int w4 = t & 31, cg = t >> 5;
    const float* xbase = x + ((size_t)nb * NC + cg * 16) * (NH * NW) + 4 * w4;
    f32x4 th0 = *(const f32x4*)(theta + cg * 16);
    f32x4 th1 = *(const f32x4*)(theta + cg * 16 + 4);
    f32x4 th2 = *(const f32x4*)(theta + cg * 16 + 8);
    f32x4 th3 = *(const f32x4*)(theta + cg * 16 + 12);
    f32x4 p0 = *(const f32x4*)(pw + cg * 16);
    f32x4 p1 = *(const f32x4*)(pw + cg * 16 + 4);
    f32x4 p2 = *(const f32x4*)(pw + cg * 16 + 8);
    f32x4 p3 = *(const f32x4*)(pw + cg * 16 + 12);
    float pwv[16] = {p0.x, p0.y, p0.z, p0.w, p1.x, p1.y, p1.z, p1.w,
                     p2.x, p2.y, p2.z, p2.w, p3.x, p3.y, p3.z, p3.w};

#pragma unroll 1
    for (int rho = 0; rho < 4; ++rho) {
        int hh = 2 * h2b + rho - 1;
        if (hh >= 0 && hh < NH) {           // block-uniform
            const float* xp = xbase + (size_t)hh * NW;
            f32x4 X[16];
#pragma unroll
            for (int cc = 0; cc < 16; ++cc) // 16 coalesced loads in flight (512B runs)
                X[cc] = *(const f32x4*)(xp + (size_t)cc * (NH * NW));
#pragma unroll
            for (int ww = 0; ww < 4; ++ww) { // register transpose -> 16B sign units
                int wp = 4 * w4 + ww + 1;
                u32x4 v;
                v.x = pk8(X[0][ww], th0.x) | (pk8(X[1][ww], th0.y) << 8) |
                      (pk8(X[2][ww], th0.z) << 16) | (pk8(X[3][ww], th0.w) << 24);
                v.y = pk8(X[4][ww], th1.x) | (pk8(X[5][ww], th1.y) << 8) |
                      (pk8(X[6][ww], th1.z) << 16) | (pk8(X[7][ww], th1.w) << 24);
                v.z = pk8(X[8][ww], th2.x) | (pk8(X[9][ww], th2.y) << 8) |
                      (pk8(X[10][ww], th2.z) << 16) | (pk8(X[11][ww], th2.w) << 24);
                v.w = pk8(X[12][ww], th3.x) | (pk8(X[13][ww], th3.y) << 8) |
                      (pk8(X[14][ww], th3.z) << 16) | (pk8(X[15][ww], th3.w) << 24);
                *(u32x4*)(AT + (size_t)(rho * WP + wp) * NC + ((cg ^ swz7(wp)) << 4)) = v;
            }
            if (rho == 1 || rho == 2) {     // shortcut while X is live (r9-validated addr)
                int s1 = hh & 1, h2 = hh >> 1;
                float* obase = out + (((size_t)nb * 256 + s1 * 2) * 64 + h2) * 64 + 2 * w4;
#pragma unroll
                for (int i = 0; i < 8; ++i) {
                    int o = 8 * cg + i;
                    float w0v = pwv[2 * i], w1v = pwv[2 * i + 1];
                    float v0 = w0v * X[2 * i][0] + w1v * X[2 * i + 1][0];
                    float v1 = w0v * X[2 * i][1] + w1v * X[2 * i + 1][1];
                    float v2 = w0v * X[2 * i][2] + w1v * X[2 * i + 1][2];
                    float v3 = w0v * X[2 * i][3] + w1v * X[2 * i + 1][3];
                    float2 a = {v0, v2}, bb = {v1, v3};
                    *(float2*)(obase + (size_t)o * 16384)        = a;   // s2=0
                    *(float2*)(obase + (size_t)o * 16384 + 4096) = bb;  // s2=1
                }
            }
        } else {                            // pad row (h2b = 0 or 63 only)
            u32x4 z = {0u, 0u, 0u, 0u};
#pragma unroll
            for (int ww = 0; ww < 4; ++ww) {
                int wp = 4 * w4 + ww + 1;
                *(u32x4*)(AT + (size_t)(rho * WP + wp) * NC + ((cg ^ swz7(wp)) << 4)) = z;
            }
        }
    }

    float sfr[4];
#pragma unroll
    for (int ni = 0; ni < 4; ++ni) sfr[ni] = sf[ni * 16 + lr];

    int h = h2b * 2 + (wid >> 1);           // output row for this wave
    int w0 = (wid & 1) * 64;                // output col base
    f32x4 acc[4][4];
    f32x4 zero = {0.f, 0.f, 0.f, 0.f};
#pragma unroll
    for (int mi = 0; mi < 4; ++mi)
#pragma unroll
        for (int ni = 0; ni < 4; ++ni) acc[mi][ni] = zero;
    __syncthreads();

    // ---- MFMA phase: per-mi swizzle at the ACTUAL column wp+16mi (the r11 fix) ----
#pragma unroll
    for (int p = 0; p < 9; ++p) {
        int kh = p / 3, kw = p % 3;         // constants after unroll
        int rho = (wid >> 1) + kh;          // local padded row 0..3
        int wp = w0 + kw + lr;
        const unsigned char* ap = AT + (size_t)(rho * WP + wp) * NC;
        const unsigned char* brow = wf + p * 8192 + l * 16;
        i64_t bfr[4][4];
#pragma unroll
        for (int kb = 0; kb < 4; ++kb) {    // B: 16B/lane coalesced, L2-hot
            i64x2 b01 = *(const i64x2*)(brow + kb * 2048);
            i64x2 b23 = *(const i64x2*)(brow + kb * 2048 + 1024);
            bfr[kb][0] = b01.x; bfr[kb][1] = b01.y;
            bfr[kb][2] = b23.x; bfr[kb][3] = b23.y;
        }
#pragma unroll
        for (int mi = 0; mi < 4; ++mi) {    // 2 x ds_read_b128 = all 4 kb fragments
            int s7m = swz7(wp + mi * 16);   // swizzle of the column actually read
            i64x2 a01 = *(const i64x2*)(ap + mi * 2048 + ((lg ^ s7m) << 4));
            i64x2 a23 = *(const i64x2*)(ap + mi * 2048 + (((lg + 4) ^ s7m) << 4));
            i64_t af[4] = {a01.x, a01.y, a23.x, a23.y};
#pragma unroll
            for (int kb = 0; kb < 4; ++kb)
#pragma unroll
                for (int ni = 0; ni < 4; ++ni)
                    acc[mi][ni] = __builtin_amdgcn_mfma_f32_16x16x32_fp8_fp8(
                        af[kb], bfr[kb][ni], acc[mi][ni], 0, 0, 0);
        }
    }
    __syncthreads();                        // A-tile dead; reuse LDS for epilogue transpose

    // ---- epilogue: out += conv*sf (r7-proven; out lines written by this block) ----
    float (*Tt)[33] = (float (*)[33])(AT + wid * 8448);
    int s1 = h & 1, h2 = h >> 1;
    float* ob = out + (((size_t)nb * 256 + s1 * 2) * 64 + h2) * 64;
    int og = l >> 5;
    int wl_lo = l & 31;
#pragma unroll
    for (int half = 0; half < 2; ++half) {
#pragma unroll
        for (int mi2 = 0; mi2 < 2; ++mi2) {
            int mi = half * 2 + mi2;
#pragma unroll
            for (int ni = 0; ni < 4; ++ni)
#pragma unroll
                for (int r = 0; r < 4; ++r)
                    Tt[ni * 16 + lr][mi2 * 16 + lg * 4 + r] = acc[mi][ni][r] * sfr[ni];
        }
        asm volatile("" ::: "memory");      // per-wave DS in-order; pin compiler order
        int w = w0 + half * 32 + wl_lo;
        int lanoff = (w & 1) * 4096 + (w >> 1);
        for (int oo = 0; oo < 32; ++oo) {
            int o = 2 * oo + og;
            ob[(size_t)o * 16384 + lanoff] += Tt[o][wl_lo];
        }
        asm volatile("" ::: "memory");      // WAR: half 1 Tt writes after half 0 reads
    }
}

extern "C" void kernel_launch(void* const* d_in, const int* in_sizes, int n_in,
                              void* d_out, int out_size, void* d_ws, size_t ws_size,
                              hipStream_t stream) {
    const float* x  = (const float*)d_in[0];
    const float* b1 = (const float*)d_in[1];
    const float* pa = (const float*)d_in[2];
    const float* b2 = (const float*)d_in[3];
    const float* cw = (const float*)d_in[4];
    const float* pw = (const float*)d_in[5];
    float* out = (float*)d_out;
    // ws layout: [0,256) sf | [256,768) theta | [768, 768+73728) wfrag  (no SB!)
    float* sf = (float*)d_ws;
    float* theta = (float*)((char*)d_ws + 256);
    unsigned char* wfr = (unsigned char*)d_ws + 768;

    k_prep<<<288, 256, 0, stream>>>(cw, b1, pa, b2, sf, theta, wfr);
    k_fused<<<1024, 256, 0, stream>>>(x, theta, pw, wfr, sf, out);
}

// Round 13
// 84.350 us; speedup vs baseline: 1.1030x; 1.1030x over previous
//
#include <hip/hip_runtime.h>
#include <stdint.h>

typedef __attribute__((ext_vector_type(4))) float f32x4;
typedef __attribute__((ext_vector_type(4))) unsigned int u32x4;
typedef __attribute__((ext_vector_type(2))) long long i64x2;
typedef long long i64_t;

#define NB 16
#define NC 128
#define NH 128
#define NW 128
#define WP 130

__device__ __forceinline__ int swz7(int wp) { return (wp ^ (wp >> 3)) & 7; }

// ---------------- prep: wfrag (B sign bytes) + sf = mean|w| + theta ----------------
// wfrag flat byte f = p*8192 + kb*2048 + nip*1024 + l*16 + nl*8 + j   (ni = nip*2+nl)
// o = ni*16 + (l&15)
// plain-unit K mapping (validated r7): instr kb, lane lg holds 8-block
// {2lg,2lg+1,2lg+8,2lg+9}[kb]  ->  c = lg*16 + (kb&1)*8 + (kb>>1)*64 + j
__global__ __launch_bounds__(256) void k_prep(const float* __restrict__ cw,
                                              const float* __restrict__ b1,
                                              const float* __restrict__ pa,
                                              const float* __restrict__ b2,
                                              float* __restrict__ sf,
                                              float* __restrict__ theta,
                                              unsigned char* __restrict__ wf) {
    int b = blockIdx.x, t = threadIdx.x;    // 288 blocks
    int f = b * 256 + t;                    // < 73728
    int j   = f & 7;
    int kb  = (f >> 11) & 3;
    int p   = f >> 13;
    int l   = (f >> 4) & 63;
    int lg = (l >> 4) & 3;
    int nl  = (f >> 3) & 1;
    int nip = (f >> 10) & 1;
    int o = (nip * 2 + nl) * 16 + (l & 15);
    int c = lg * 16 + (kb & 1) * 8 + (kb >> 1) * 64 + j;   // plain-unit K mapping
    float wv = cw[o * 1152 + c * 9 + p];
    wf[f] = wv > 0.f ? (unsigned char)0x38
                     : (wv < 0.f ? (unsigned char)0xB8 : (unsigned char)0x00);
    if (b < 64) {                           // sf[b] = mean|w| over 1152
        __shared__ float red[4];
        const float* pp = cw + b * 1152;
        float s = 0.f;
        for (int i = t; i < 1152; i += 256) s += fabsf(pp[i]);
#pragma unroll
        for (int off = 32; off > 0; off >>= 1) s += __shfl_down(s, off);
        if ((t & 63) == 0) red[t >> 6] = s;
        __syncthreads();
        if (t == 0) sf[b] = (red[0] + red[1] + red[2] + red[3]) * (1.0f / 1152.0f);
    }
    if (b == 64 && t < NC) {                // theta: sign(prelu(v+b1)+b2) == sign(v - theta)
        float B1 = b1[t], A = pa[t], B2 = b2[t];   // prelu slope a>0 -> monotone
        theta[t] = (-B2 >= 0.f) ? (-B1 - B2) : (-B1 - B2 / A);
    }
}

__device__ __forceinline__ unsigned int pk8(float v, float th) {
    return v > th ? 0x38u : (v < th ? 0xB8u : 0u);
}

// ---------------- fused: stage signs of 4 padded x-rows into LDS (coalesced f32x4,
// register transpose, two-sided swz7 at the actual column), implicit-GEMM fp8 MFMA,
// epilogue SINGLE write: out = conv*sf + pw.x (batched x loads, L3-hot). ----------------
__global__ __launch_bounds__(256, 2) void k_fused(
    const float* __restrict__ x, const float* __restrict__ theta,
    const float* __restrict__ pw, const unsigned char* __restrict__ wf,
    const float* __restrict__ sf, float* __restrict__ out) {
    __shared__ __align__(16) unsigned char AT[4 * WP * NC];   // 66560 B
    int bxr = blockIdx.x;
    int bx = (bxr & 7) * 128 + (bxr >> 3);  // XCD swizzle (1024 % 8 == 0, bijective)
    int nb = bx >> 6;
    int h2b = bx & 63;
    int t = threadIdx.x;
    int wid = t >> 6;
    int l = t & 63;
    int lr = l & 15, lg = l >> 4;

    // ---- pad columns wp=0, 129 (zeros, swizzled slots) ----
    if (t < 64) {
        int rho = t >> 4, side = (t >> 3) & 1, u = t & 7;
        int wp = side ? (WP - 1) : 0;
        u32x4 z = {0u, 0u, 0u, 0u};
        *(u32x4*)(AT + (size_t)(rho * WP + wp) * NC + ((u ^ swz7(wp)) << 4)) = z;
    }

    // ---- staging: thread (w4 = t&31, cg = t>>5), 16 f32x4 loads per row ----
    int w4 = t & 31, cg = t >> 5;
    const float* xbase = x + ((size_t)nb * NC + cg * 16) * (NH * NW) + 4 * w4;
    f32x4 th0 = *(const f32x4*)(theta + cg * 16);
    f32x4 th1 = *(const f32x4*)(theta + cg * 16 + 4);
    f32x4 th2 = *(const f32x4*)(theta + cg * 16 + 8);
    f32x4 th3 = *(const f32x4*)(theta + cg * 16 + 12);

#pragma unroll 1
    for (int rho = 0; rho < 4; ++rho) {
        int hh = 2 * h2b + rho - 1;
        if (hh >= 0 && hh < NH) {           // block-uniform
            const float* xp = xbase + (size_t)hh * NW;
            f32x4 X[16];
#pragma unroll
            for (int cc = 0; cc < 16; ++cc) // 16 coalesced loads in flight (512B runs)
                X[cc] = *(const f32x4*)(xp + (size_t)cc * (NH * NW));
#pragma unroll
            for (int ww = 0; ww < 4; ++ww) { // register transpose -> 16B sign units
                int wp = 4 * w4 + ww + 1;
                u32x4 v;
                v.x = pk8(X[0][ww], th0.x) | (pk8(X[1][ww], th0.y) << 8) |
                      (pk8(X[2][ww], th0.z) << 16) | (pk8(X[3][ww], th0.w) << 24);
                v.y = pk8(X[4][ww], th1.x) | (pk8(X[5][ww], th1.y) << 8) |
                      (pk8(X[6][ww], th1.z) << 16) | (pk8(X[7][ww], th1.w) << 24);
                v.z = pk8(X[8][ww], th2.x) | (pk8(X[9][ww], th2.y) << 8) |
                      (pk8(X[10][ww], th2.z) << 16) | (pk8(X[11][ww], th2.w) << 24);
                v.w = pk8(X[12][ww], th3.x) | (pk8(X[13][ww], th3.y) << 8) |
                      (pk8(X[14][ww], th3.z) << 16) | (pk8(X[15][ww], th3.w) << 24);
                *(u32x4*)(AT + (size_t)(rho * WP + wp) * NC + ((cg ^ swz7(wp)) << 4)) = v;
            }
        } else {                            // pad row (h2b = 0 or 63 only)
            u32x4 z = {0u, 0u, 0u, 0u};
#pragma unroll
            for (int ww = 0; ww < 4; ++ww) {
                int wp = 4 * w4 + ww + 1;
                *(u32x4*)(AT + (size_t)(rho * WP + wp) * NC + ((cg ^ swz7(wp)) << 4)) = z;
            }
        }
    }

    float sfr[4];
#pragma unroll
    for (int ni = 0; ni < 4; ++ni) sfr[ni] = sf[ni * 16 + lr];

    int h = h2b * 2 + (wid >> 1);           // output row for this wave
    int w0 = (wid & 1) * 64;                // output col base
    f32x4 acc[4][4];
    f32x4 zero = {0.f, 0.f, 0.f, 0.f};
#pragma unroll
    for (int mi = 0; mi < 4; ++mi)
#pragma unroll
        for (int ni = 0; ni < 4; ++ni) acc[mi][ni] = zero;
    __syncthreads();

    // ---- MFMA phase: per-mi swizzle at the ACTUAL column wp+16mi (r12-proven) ----
#pragma unroll
    for (int p = 0; p < 9; ++p) {
        int kh = p / 3, kw = p % 3;         // constants after unroll
        int rho = (wid >> 1) + kh;          // local padded row 0..3
        int wp = w0 + kw + lr;
        const unsigned char* ap = AT + (size_t)(rho * WP + wp) * NC;
        const unsigned char* brow = wf + p * 8192 + l * 16;
        i64_t bfr[4][4];
#pragma unroll
        for (int kb = 0; kb < 4; ++kb) {    // B: 16B/lane coalesced, L2-hot
            i64x2 b01 = *(const i64x2*)(brow + kb * 2048);
            i64x2 b23 = *(const i64x2*)(brow + kb * 2048 + 1024);
            bfr[kb][0] = b01.x; bfr[kb][1] = b01.y;
            bfr[kb][2] = b23.x; bfr[kb][3] = b23.y;
        }
#pragma unroll
        for (int mi = 0; mi < 4; ++mi) {    // 2 x ds_read_b128 = all 4 kb fragments
            int s7m = swz7(wp + mi * 16);   // swizzle of the column actually read
            i64x2 a01 = *(const i64x2*)(ap + mi * 2048 + ((lg ^ s7m) << 4));
            i64x2 a23 = *(const i64x2*)(ap + mi * 2048 + (((lg + 4) ^ s7m) << 4));
            i64_t af[4] = {a01.x, a01.y, a23.x, a23.y};
#pragma unroll
            for (int kb = 0; kb < 4; ++kb)
#pragma unroll
                for (int ni = 0; ni < 4; ++ni)
                    acc[mi][ni] = __builtin_amdgcn_mfma_f32_16x16x32_fp8_fp8(
                        af[kb], bfr[kb][ni], acc[mi][ni], 0, 0, 0);
        }
    }
    __syncthreads();                        // A-tile dead; reuse LDS for epilogue transpose

    // ---- epilogue: out = conv*sf + pw.x, SINGLE write, 16-deep batched x loads (r10) ----
    float (*Tt)[33] = (float (*)[33])(AT + wid * 8448);
    int s1 = h & 1, h2 = h >> 1;
    float* ob = out + (((size_t)nb * 256 + s1 * 2) * 64 + h2) * 64;
    const float* xb2 = x + ((size_t)nb * NC * NH + h) * NW;   // + c*16384 + w
    int og = l >> 5;
    int wl_lo = l & 31;
#pragma unroll
    for (int half = 0; half < 2; ++half) {
#pragma unroll
        for (int mi2 = 0; mi2 < 2; ++mi2) {
            int mi = half * 2 + mi2;
#pragma unroll
            for (int ni = 0; ni < 4; ++ni)
#pragma unroll
                for (int r = 0; r < 4; ++r)
                    Tt[ni * 16 + lr][mi2 * 16 + lg * 4 + r] = acc[mi][ni][r] * sfr[ni];
        }
        asm volatile("" ::: "memory");      // per-wave DS in-order; pin compiler order
        int w = w0 + half * 32 + wl_lo;
        int lanoff = (w & 1) * 4096 + (w >> 1);
#pragma unroll
        for (int grp = 0; grp < 4; ++grp) { // 8 outputs per group, 16 x-loads in flight
            float xa[8], xb[8];
            float2 pv[8];
#pragma unroll
            for (int q = 0; q < 8; ++q) {
                int o = 2 * (grp * 8 + q) + og;
                xa[q] = xb2[(size_t)(2 * o) * 16384 + w];      // L3-hot (staged above)
                xb[q] = xb2[(size_t)(2 * o + 1) * 16384 + w];
                pv[q] = *(const float2*)(pw + 2 * o);          // L1-hot
            }
#pragma unroll
            for (int q = 0; q < 8; ++q) {
                int o = 2 * (grp * 8 + q) + og;
                ob[(size_t)o * 16384 + lanoff] =
                    Tt[o][wl_lo] + pv[q].x * xa[q] + pv[q].y * xb[q];
            }
        }
        asm volatile("" ::: "memory");      // WAR: half 1 Tt writes after half 0 reads
    }
}

extern "C" void kernel_launch(void* const* d_in, const int* in_sizes, int n_in,
                              void* d_out, int out_size, void* d_ws, size_t ws_size,
                              hipStream_t stream) {
    const float* x  = (const float*)d_in[0];
    const float* b1 = (const float*)d_in[1];
    const float* pa = (const float*)d_in[2];
    const float* b2 = (const float*)d_in[3];
    const float* cw = (const float*)d_in[4];
    const float* pw = (const float*)d_in[5];
    float* out = (float*)d_out;
    // ws layout: [0,256) sf | [256,768) theta | [768, 768+73728) wfrag  (no SB!)
    float* sf = (float*)d_ws;
    float* theta = (float*)((char*)d_ws + 256);
    unsigned char* wfr = (unsigned char*)d_ws + 768;

    k_prep<<<288, 256, 0, stream>>>(cw, b1, pa, b2, sf, theta, wfr);
    k_fused<<<1024, 256, 0, stream>>>(x, theta, pw, wfr, sf, out);
}

// Round 14
// 82.523 us; speedup vs baseline: 1.1275x; 1.0221x over previous
//
#include <hip/hip_runtime.h>
#include <stdint.h>

typedef __attribute__((ext_vector_type(4))) float f32x4;
typedef __attribute__((ext_vector_type(4))) unsigned int u32x4;
typedef __attribute__((ext_vector_type(2))) long long i64x2;
typedef long long i64_t;

#define NB 16
#define NC 128
#define NH 128
#define NW 128
#define WP 130

__device__ __forceinline__ int swz7(int wp) { return (wp ^ (wp >> 3)) & 7; }

// ---------------- prep: wfrag (B sign bytes) + sf = mean|w| + theta ----------------
// wfrag flat byte f = p*8192 + kb*2048 + nip*1024 + l*16 + nl*8 + j   (ni = nip*2+nl)
// o = ni*16 + (l&15)
// plain-unit K mapping (validated r7): instr kb, lane lg holds 8-block
// {2lg,2lg+1,2lg+8,2lg+9}[kb]  ->  c = lg*16 + (kb&1)*8 + (kb>>1)*64 + j
__global__ __launch_bounds__(256) void k_prep(const float* __restrict__ cw,
                                              const float* __restrict__ b1,
                                              const float* __restrict__ pa,
                                              const float* __restrict__ b2,
                                              float* __restrict__ sf,
                                              float* __restrict__ theta,
                                              unsigned char* __restrict__ wf) {
    int b = blockIdx.x, t = threadIdx.x;    // 288 blocks
    int f = b * 256 + t;                    // < 73728
    int j   = f & 7;
    int kb  = (f >> 11) & 3;
    int p   = f >> 13;
    int l   = (f >> 4) & 63;
    int lg = (l >> 4) & 3;
    int nl  = (f >> 3) & 1;
    int nip = (f >> 10) & 1;
    int o = (nip * 2 + nl) * 16 + (l & 15);
    int c = lg * 16 + (kb & 1) * 8 + (kb >> 1) * 64 + j;   // plain-unit K mapping
    float wv = cw[o * 1152 + c * 9 + p];
    wf[f] = wv > 0.f ? (unsigned char)0x38
                     : (wv < 0.f ? (unsigned char)0xB8 : (unsigned char)0x00);
    if (b < 64) {                           // sf[b] = mean|w| over 1152
        __shared__ float red[4];
        const float* pp = cw + b * 1152;
        float s = 0.f;
        for (int i = t; i < 1152; i += 256) s += fabsf(pp[i]);
#pragma unroll
        for (int off = 32; off > 0; off >>= 1) s += __shfl_down(s, off);
        if ((t & 63) == 0) red[t >> 6] = s;
        __syncthreads();
        if (t == 0) sf[b] = (red[0] + red[1] + red[2] + red[3]) * (1.0f / 1152.0f);
    }
    if (b == 64 && t < NC) {                // theta: sign(prelu(v+b1)+b2) == sign(v - theta)
        float B1 = b1[t], A = pa[t], B2 = b2[t];   // prelu slope a>0 -> monotone
        theta[t] = (-B2 >= 0.f) ? (-B1 - B2) : (-B1 - B2 / A);
    }
}

__device__ __forceinline__ unsigned int pk8(float v, float th) {
    return v > th ? 0x38u : (v < th ? 0xB8u : 0u);
}

// ---------------- fused: stage signs of 4 padded x-rows into LDS (coalesced f32x4,
// register transpose, two-sided swz7), shortcut held in 64 REGISTERS (sc0/sc1),
// implicit-GEMM fp8 MFMA, epilogue: full per-wave Tt tile -> barrier ->
// staging-mapped ds_read_b128 + reg-shortcut add -> single coalesced out write.
// No global reads in the epilogue. ----------------
__global__ __launch_bounds__(256, 2) void k_fused(
    const float* __restrict__ x, const float* __restrict__ theta,
    const float* __restrict__ pw, const unsigned char* __restrict__ wf,
    const float* __restrict__ sf, float* __restrict__ out) {
    __shared__ __align__(16) unsigned char AT[69632];   // staging 66560 | Tt 4x17408
    int bxr = blockIdx.x;
    int bx = (bxr & 7) * 128 + (bxr >> 3);  // XCD swizzle (1024 % 8 == 0, bijective)
    int nb = bx >> 6;
    int h2b = bx & 63;
    int t = threadIdx.x;
    int wid = t >> 6;
    int l = t & 63;
    int lr = l & 15, lg = l >> 4;

    // ---- pad columns wp=0, 129 (zeros, swizzled slots) ----
    if (t < 64) {
        int rho = t >> 4, side = (t >> 3) & 1, u = t & 7;
        int wp = side ? (WP - 1) : 0;
        u32x4 z = {0u, 0u, 0u, 0u};
        *(u32x4*)(AT + (size_t)(rho * WP + wp) * NC + ((u ^ swz7(wp)) << 4)) = z;
    }

    // ---- staging: thread (w4 = t&31, cg = t>>5) ----
    int w4 = t & 31, cg = t >> 5;
    const float* xbase = x + ((size_t)nb * NC + cg * 16) * (NH * NW) + 4 * w4;
    f32x4 th0 = *(const f32x4*)(theta + cg * 16);
    f32x4 th1 = *(const f32x4*)(theta + cg * 16 + 4);
    f32x4 th2 = *(const f32x4*)(theta + cg * 16 + 8);
    f32x4 th3 = *(const f32x4*)(theta + cg * 16 + 12);
    f32x4 p0 = *(const f32x4*)(pw + cg * 16);
    f32x4 p1 = *(const f32x4*)(pw + cg * 16 + 4);
    f32x4 p2 = *(const f32x4*)(pw + cg * 16 + 8);
    f32x4 p3 = *(const f32x4*)(pw + cg * 16 + 12);
    float pwv[16] = {p0.x, p0.y, p0.z, p0.w, p1.x, p1.y, p1.z, p1.w,
                     p2.x, p2.y, p2.z, p2.w, p3.x, p3.y, p3.z, p3.w};
    float sc0[8][4], sc1[8][4];             // shortcut regs, statically indexed

#define LOADX(HH) \
    { const float* xp = xbase + (size_t)(HH) * NW; \
      _Pragma("unroll") for (int cc = 0; cc < 16; ++cc) \
          X[cc] = *(const f32x4*)(xp + (size_t)cc * (NH * NW)); }
#define PACKROW(RHO) \
    _Pragma("unroll") for (int ww = 0; ww < 4; ++ww) { \
        int wp = 4 * w4 + ww + 1; \
        u32x4 v; \
        v.x = pk8(X[0][ww], th0.x) | (pk8(X[1][ww], th0.y) << 8) | \
              (pk8(X[2][ww], th0.z) << 16) | (pk8(X[3][ww], th0.w) << 24); \
        v.y = pk8(X[4][ww], th1.x) | (pk8(X[5][ww], th1.y) << 8) | \
              (pk8(X[6][ww], th1.z) << 16) | (pk8(X[7][ww], th1.w) << 24); \
        v.z = pk8(X[8][ww], th2.x) | (pk8(X[9][ww], th2.y) << 8) | \
              (pk8(X[10][ww], th2.z) << 16) | (pk8(X[11][ww], th2.w) << 24); \
        v.w = pk8(X[12][ww], th3.x) | (pk8(X[13][ww], th3.y) << 8) | \
              (pk8(X[14][ww], th3.z) << 16) | (pk8(X[15][ww], th3.w) << 24); \
        *(u32x4*)(AT + (size_t)((RHO) * WP + wp) * NC + ((cg ^ swz7(wp)) << 4)) = v; \
    }
#define ZEROROW(RHO) \
    { u32x4 z = {0u, 0u, 0u, 0u}; \
      _Pragma("unroll") for (int ww = 0; ww < 4; ++ww) { \
          int wp = 4 * w4 + ww + 1; \
          *(u32x4*)(AT + (size_t)((RHO) * WP + wp) * NC + ((cg ^ swz7(wp)) << 4)) = z; } }
#define SCROW(SC) \
    _Pragma("unroll") for (int i = 0; i < 8; ++i) { \
        float wa = pwv[2 * i], wb = pwv[2 * i + 1]; \
        _Pragma("unroll") for (int ww = 0; ww < 4; ++ww) \
            SC[i][ww] = wa * X[2 * i][ww] + wb * X[2 * i + 1][ww]; \
    }

    if (h2b > 0) {                          // row 0 (top halo)
        f32x4 X[16];
        LOADX(2 * h2b - 1)
        PACKROW(0)
    } else ZEROROW(0)
    {                                       // row 1 = output row 0 (+shortcut regs)
        f32x4 X[16];
        LOADX(2 * h2b)
        PACKROW(1)
        SCROW(sc0)
    }
    {                                       // row 2 = output row 1 (+shortcut regs)
        f32x4 X[16];
        LOADX(2 * h2b + 1)
        PACKROW(2)
        SCROW(sc1)
    }
    if (h2b < 63) {                         // row 3 (bottom halo)
        f32x4 X[16];
        LOADX(2 * h2b + 2)
        PACKROW(3)
    } else ZEROROW(3)

    float sfr[4];
#pragma unroll
    for (int ni = 0; ni < 4; ++ni) sfr[ni] = sf[ni * 16 + lr];

    int w0 = (wid & 1) * 64;                // output col base for this wave
    f32x4 acc[4][4];
    f32x4 zero = {0.f, 0.f, 0.f, 0.f};
#pragma unroll
    for (int mi = 0; mi < 4; ++mi)
#pragma unroll
        for (int ni = 0; ni < 4; ++ni) acc[mi][ni] = zero;
    __syncthreads();

    // ---- MFMA phase: per-mi swizzle at the actual column (r12/r13-proven) ----
#pragma unroll
    for (int p = 0; p < 9; ++p) {
        int kh = p / 3, kw = p % 3;         // constants after unroll
        int rho = (wid >> 1) + kh;          // local padded row 0..3
        int wp = w0 + kw + lr;
        const unsigned char* ap = AT + (size_t)(rho * WP + wp) * NC;
        const unsigned char* brow = wf + p * 8192 + l * 16;
        i64_t bfr[4][4];
#pragma unroll
        for (int kb = 0; kb < 4; ++kb) {    // B: 16B/lane coalesced, L2-hot
            i64x2 b01 = *(const i64x2*)(brow + kb * 2048);
            i64x2 b23 = *(const i64x2*)(brow + kb * 2048 + 1024);
            bfr[kb][0] = b01.x; bfr[kb][1] = b01.y;
            bfr[kb][2] = b23.x; bfr[kb][3] = b23.y;
        }
#pragma unroll
        for (int mi = 0; mi < 4; ++mi) {    // 2 x ds_read_b128 = all 4 kb fragments
            int s7m = swz7(wp + mi * 16);   // swizzle of the column actually read
            i64x2 a01 = *(const i64x2*)(ap + mi * 2048 + ((lg ^ s7m) << 4));
            i64x2 a23 = *(const i64x2*)(ap + mi * 2048 + (((lg + 4) ^ s7m) << 4));
            i64_t af[4] = {a01.x, a01.y, a23.x, a23.y};
#pragma unroll
            for (int kb = 0; kb < 4; ++kb)
#pragma unroll
                for (int ni = 0; ni < 4; ++ni)
                    acc[mi][ni] = __builtin_amdgcn_mfma_f32_16x16x32_fp8_fp8(
                        af[kb], bfr[kb][ni], acc[mi][ni], 0, 0, 0);
        }
    }
    __syncthreads();                        // A-tile dead; AT becomes 4 x Tt[64][68]

    // ---- epilogue: full per-wave conv tile (f32x4 LDS writes, stride 68 = 16B-aligned) ----
    float (*Tt)[68] = (float (*)[68])(AT + wid * 17408);
#pragma unroll
    for (int mi = 0; mi < 4; ++mi)
#pragma unroll
        for (int ni = 0; ni < 4; ++ni)
            *(f32x4*)&Tt[ni * 16 + lr][mi * 16 + lg * 4] = acc[mi][ni] * sfr[ni];
    __syncthreads();

    // staging-mapped readout: thread (w4, cg) owns o in [8cg,8cg+8), cols 4w4..+3
    int wha = w4 >> 4, w4l = w4 & 15;
#define EPIROW(R2, SC) { \
    const float (*Ts)[68] = (const float (*)[68])(AT + ((R2) * 2 + wha) * 17408); \
    float* obr = out + (((size_t)nb * 256 + (R2) * 2) * 64 + h2b) * 64 + 2 * w4; \
    _Pragma("unroll") for (int i = 0; i < 8; ++i) { \
        int o = 8 * cg + i; \
        f32x4 cv = *(const f32x4*)&Ts[o][4 * w4l]; \
        float2 A = {cv.x + SC[i][0], cv.z + SC[i][2]}; \
        float2 B = {cv.y + SC[i][1], cv.w + SC[i][3]}; \
        *(float2*)(obr + (size_t)o * 16384)        = A; \
        *(float2*)(obr + (size_t)o * 16384 + 4096) = B; \
    } }
    EPIROW(0, sc0)
    EPIROW(1, sc1)
}

extern "C" void kernel_launch(void* const* d_in, const int* in_sizes, int n_in,
                              void* d_out, int out_size, void* d_ws, size_t ws_size,
                              hipStream_t stream) {
    const float* x  = (const float*)d_in[0];
    const float* b1 = (const float*)d_in[1];
    const float* pa = (const float*)d_in[2];
    const float* b2 = (const float*)d_in[3];
    const float* cw = (const float*)d_in[4];
    const float* pw = (const float*)d_in[5];
    float* out = (float*)d_out;
    // ws layout: [0,256) sf | [256,768) theta | [768, 768+73728) wfrag
    float* sf = (float*)d_ws;
    float* theta = (float*)((char*)d_ws + 256);
    unsigned char* wfr = (unsigned char*)d_ws + 768;

    k_prep<<<288, 256, 0, stream>>>(cw, b1, pa, b2, sf, theta, wfr);
    k_fused<<<1024, 256, 0, stream>>>(x, theta, pw, wfr, sf, out);
}